// Round 1
// baseline (237.426 us; speedup 1.0000x reference)
//
#include <hip/hip_runtime.h>

#define NEAR0f 1e-8f
#define REGf   0.002f

__device__ __forceinline__ float wave_reduce(float v) {
#pragma unroll
    for (int off = 32; off > 0; off >>= 1)
        v += __shfl_down(v, off, 64);
    return v;
}

// One fused pass over all three inputs: NLL terms, sum(W1^2), sum(W2^2).
// Vectorized 16B loads; per-lane select (no divergence); block reduce;
// one atomicAdd per block per accumulator.
__global__ __launch_bounds__(256) void reduce_all(
    const float4* __restrict__ p4,
    const int4*   __restrict__ l4,
    const float4* __restrict__ w1,
    const float4* __restrict__ w2,
    float* __restrict__ acc,
    int n4, int w4)
{
    const int tid    = blockIdx.x * blockDim.x + threadIdx.x;
    const int stride = gridDim.x * blockDim.x;

    float nll = 0.0f;
    for (int i = tid; i < n4; i += stride) {
        float4 p = p4[i];
        int4   l = l4[i];
        float a0 = l.x ? p.x : 1.0f - p.x;
        float a1 = l.y ? p.y : 1.0f - p.y;
        float a2 = l.z ? p.z : 1.0f - p.z;
        float a3 = l.w ? p.w : 1.0f - p.w;
        nll -= __logf(fmaxf(a0, NEAR0f));
        nll -= __logf(fmaxf(a1, NEAR0f));
        nll -= __logf(fmaxf(a2, NEAR0f));
        nll -= __logf(fmaxf(a3, NEAR0f));
    }

    float s1 = 0.0f, s2 = 0.0f;
    for (int i = tid; i < w4; i += stride) {
        float4 a = w1[i];
        float4 b = w2[i];
        s1 = fmaf(a.x, a.x, fmaf(a.y, a.y, fmaf(a.z, a.z, fmaf(a.w, a.w, s1))));
        s2 = fmaf(b.x, b.x, fmaf(b.y, b.y, fmaf(b.z, b.z, fmaf(b.w, b.w, s2))));
    }

    nll = wave_reduce(nll);
    s1  = wave_reduce(s1);
    s2  = wave_reduce(s2);

    __shared__ float sm[3][4];
    const int lane = threadIdx.x & 63;
    const int wave = threadIdx.x >> 6;
    if (lane == 0) { sm[0][wave] = nll; sm[1][wave] = s1; sm[2][wave] = s2; }
    __syncthreads();
    if (threadIdx.x == 0) {
        atomicAdd(&acc[0], sm[0][0] + sm[0][1] + sm[0][2] + sm[0][3]);
        atomicAdd(&acc[1], sm[1][0] + sm[1][1] + sm[1][2] + sm[1][3]);
        atomicAdd(&acc[2], sm[2][0] + sm[2][1] + sm[2][2] + sm[2][3]);
    }
}

// ws is poisoned 0xAA before every launch — must zero accumulators ourselves.
__global__ void init_acc(float* acc) {
    acc[0] = 0.0f; acc[1] = 0.0f; acc[2] = 0.0f;
}

__global__ void finalize(const float* __restrict__ acc, float* __restrict__ out,
                         float invN) {
    out[0] = acc[0] * invN + REGf * (sqrtf(acc[1]) + sqrtf(acc[2]));
}

extern "C" void kernel_launch(void* const* d_in, const int* in_sizes, int n_in,
                              void* d_out, int out_size, void* d_ws, size_t ws_size,
                              hipStream_t stream) {
    const float* out1  = (const float*)d_in[0];   // [N,1] fp32
    const int*   label = (const int*)d_in[1];     // [N] int
    const float* W1    = (const float*)d_in[2];   // [1024,4096] fp32
    const float* W2    = (const float*)d_in[3];   // [4096,1024] fp32

    const int N  = in_sizes[0];
    const int n4 = N / 4;
    const int w4 = in_sizes[2] / 4;               // W1 and W2 same size

    float* acc = (float*)d_ws;

    init_acc<<<1, 1, 0, stream>>>(acc);
    reduce_all<<<2048, 256, 0, stream>>>(
        (const float4*)out1, (const int4*)label,
        (const float4*)W1,   (const float4*)W2,
        acc, n4, w4);
    finalize<<<1, 1, 0, stream>>>(acc, (float*)d_out, 1.0f / (float)N);
}

// Round 2
// 191.092 us; speedup vs baseline: 1.2425x; 1.2425x over previous
//
#include <hip/hip_runtime.h>

#define NEAR0f 1e-8f
#define REGf   0.002f

typedef float __attribute__((ext_vector_type(4))) f32x4;
typedef int   __attribute__((ext_vector_type(4))) i32x4;

__device__ __forceinline__ f32x4 ntload(const f32x4* p) { return __builtin_nontemporal_load(p); }
__device__ __forceinline__ i32x4 ntload(const i32x4* p) { return __builtin_nontemporal_load(p); }

__device__ __forceinline__ float wave_reduce(float v) {
#pragma unroll
    for (int off = 32; off > 0; off >>= 1)
        v += __shfl_down(v, off, 64);
    return v;
}

// sum of -log(selected prob) over 4 elements, tree-summed
__device__ __forceinline__ float nll4(f32x4 p, i32x4 l) {
    float a0 = l.x ? p.x : 1.0f - p.x;
    float a1 = l.y ? p.y : 1.0f - p.y;
    float a2 = l.z ? p.z : 1.0f - p.z;
    float a3 = l.w ? p.w : 1.0f - p.w;
    float g0 = __logf(fmaxf(a0, NEAR0f)) + __logf(fmaxf(a1, NEAR0f));
    float g1 = __logf(fmaxf(a2, NEAR0f)) + __logf(fmaxf(a3, NEAR0f));
    return g0 + g1;
}

__device__ __forceinline__ float sq4(f32x4 a, float acc) {
    return fmaf(a.x, a.x, fmaf(a.y, a.y, fmaf(a.z, a.z, fmaf(a.w, a.w, acc))));
}

// Fused pass: NLL terms + sum(W1^2) + sum(W2^2).
// 4x-unrolled batched loads (8 independent 16B loads in flight before first use)
// to fix the MLP starvation seen in round 1 (12 VGPRs, vmcnt(0) per iter).
__global__ __launch_bounds__(256) void reduce_all(
    const f32x4* __restrict__ p4,
    const i32x4* __restrict__ l4,
    const f32x4* __restrict__ w1,
    const f32x4* __restrict__ w2,
    float* __restrict__ acc,
    int n4, int w4)
{
    const int tid    = blockIdx.x * blockDim.x + threadIdx.x;
    const int stride = gridDim.x * blockDim.x;

    float nll0 = 0.0f, nll1 = 0.0f, nll2 = 0.0f, nll3 = 0.0f;
    int i = tid;
    for (; i + 3 * stride < n4; i += 4 * stride) {
        f32x4 p0 = ntload(p4 + i);
        f32x4 p1 = ntload(p4 + i + stride);
        f32x4 p2 = ntload(p4 + i + 2 * stride);
        f32x4 p3 = ntload(p4 + i + 3 * stride);
        i32x4 l0 = ntload(l4 + i);
        i32x4 l1 = ntload(l4 + i + stride);
        i32x4 l2 = ntload(l4 + i + 2 * stride);
        i32x4 l3 = ntload(l4 + i + 3 * stride);
        nll0 -= nll4(p0, l0);
        nll1 -= nll4(p1, l1);
        nll2 -= nll4(p2, l2);
        nll3 -= nll4(p3, l3);
    }
    for (; i < n4; i += stride) {
        nll0 -= nll4(ntload(p4 + i), ntload(l4 + i));
    }
    float nll = (nll0 + nll1) + (nll2 + nll3);

    float s1a = 0.0f, s1b = 0.0f, s2a = 0.0f, s2b = 0.0f;
    int j = tid;
    for (; j + 3 * stride < w4; j += 4 * stride) {
        f32x4 a0 = ntload(w1 + j);
        f32x4 a1 = ntload(w1 + j + stride);
        f32x4 a2 = ntload(w1 + j + 2 * stride);
        f32x4 a3 = ntload(w1 + j + 3 * stride);
        f32x4 b0 = ntload(w2 + j);
        f32x4 b1 = ntload(w2 + j + stride);
        f32x4 b2 = ntload(w2 + j + 2 * stride);
        f32x4 b3 = ntload(w2 + j + 3 * stride);
        s1a = sq4(a0, s1a); s1b = sq4(a1, s1b);
        s1a = sq4(a2, s1a); s1b = sq4(a3, s1b);
        s2a = sq4(b0, s2a); s2b = sq4(b1, s2b);
        s2a = sq4(b2, s2a); s2b = sq4(b3, s2b);
    }
    for (; j < w4; j += stride) {
        s1a = sq4(ntload(w1 + j), s1a);
        s2a = sq4(ntload(w2 + j), s2a);
    }
    float s1 = s1a + s1b;
    float s2 = s2a + s2b;

    nll = wave_reduce(nll);
    s1  = wave_reduce(s1);
    s2  = wave_reduce(s2);

    __shared__ float sm[3][4];
    const int lane = threadIdx.x & 63;
    const int wave = threadIdx.x >> 6;
    if (lane == 0) { sm[0][wave] = nll; sm[1][wave] = s1; sm[2][wave] = s2; }
    __syncthreads();
    if (threadIdx.x == 0) {
        atomicAdd(&acc[0], sm[0][0] + sm[0][1] + sm[0][2] + sm[0][3]);
        atomicAdd(&acc[1], sm[1][0] + sm[1][1] + sm[1][2] + sm[1][3]);
        atomicAdd(&acc[2], sm[2][0] + sm[2][1] + sm[2][2] + sm[2][3]);
    }
}

// d_ws is poisoned 0xAA before every launch — zero accumulators ourselves.
__global__ void init_acc(float* acc) {
    acc[0] = 0.0f; acc[1] = 0.0f; acc[2] = 0.0f;
}

__global__ void finalize(const float* __restrict__ acc, float* __restrict__ out,
                         float invN) {
    out[0] = acc[0] * invN + REGf * (sqrtf(acc[1]) + sqrtf(acc[2]));
}

extern "C" void kernel_launch(void* const* d_in, const int* in_sizes, int n_in,
                              void* d_out, int out_size, void* d_ws, size_t ws_size,
                              hipStream_t stream) {
    const float* out1  = (const float*)d_in[0];   // [N,1] fp32
    const int*   label = (const int*)d_in[1];     // [N] int32
    const float* W1    = (const float*)d_in[2];   // [1024,4096] fp32
    const float* W2    = (const float*)d_in[3];   // [4096,1024] fp32

    const int N  = in_sizes[0];
    const int n4 = N / 4;
    const int w4 = in_sizes[2] / 4;               // W1 and W2 same size

    float* acc = (float*)d_ws;

    init_acc<<<1, 1, 0, stream>>>(acc);
    // 1024 blocks x 256: N-loop = 16 iters/thread (4 unrolled batches),
    // W-loop = 4 iters/thread (1 batch). 4 blocks/CU.
    reduce_all<<<1024, 256, 0, stream>>>(
        (const f32x4*)out1, (const i32x4*)label,
        (const f32x4*)W1,   (const f32x4*)W2,
        acc, n4, w4);
    finalize<<<1, 1, 0, stream>>>(acc, (float*)d_out, 1.0f / (float)N);
}